// Round 1
// 637.881 us; speedup vs baseline: 1.0015x; 1.0015x over previous
//
#include <hip/hip_runtime.h>
#include <hip/hip_bf16.h>
#include <math.h>

constexpr int kB   = 4;
constexpr int kNC  = 1024;
constexpr int kNP  = 32768;
constexpr int kC   = 256;
constexpr int kDIN = 448;
constexpr int kM   = 4;

typedef __attribute__((ext_vector_type(8))) short short8;
typedef __attribute__((ext_vector_type(4))) float float4v;
typedef __attribute__((ext_vector_type(4))) unsigned short ushort4v;

__device__ __forceinline__ float gelu_exact(float x) {
    return 0.5f * x * (1.0f + erff(x * 0.70710678118654752440f));
}
__device__ __forceinline__ unsigned short f2bf(float f) {
    unsigned int u = __float_as_uint(f);
    unsigned int r = (u + 0x7fffu + ((u >> 16) & 1u)) >> 16;
    return (unsigned short)r;
}
__device__ __forceinline__ float bf2f(unsigned short s) {
    return __uint_as_float(((unsigned int)s) << 16);
}
// packed f32x2 -> bf16x2 (v_cvt_pk_bf16_f32 on gfx950 via hip_bf16)
__device__ __forceinline__ unsigned int pk_bf16(float lo, float hi) {
    __hip_bfloat162 h = __float22bfloat162_rn(float2{lo, hi});
    union { __hip_bfloat162 h; unsigned int u; } c;
    c.h = h;
    return c.u;
}

// ---------------------------------------------------------------------------
// prep: convert weights to bf16 chunked layout ws[c][n][kk], n in [0,256),
// kk in [0,32). Coalesced reads (256 threads sweep n for each k-row).
// 60 blocks: ew0(14) ew1(8) ew2(8) W0a(8) W0b(14) uw1(8)
// ---------------------------------------------------------------------------
__global__ __launch_bounds__(256) void prep_weights(
    const float* __restrict__ ew0, const float* __restrict__ ew1,
    const float* __restrict__ ew2, const float* __restrict__ uw0,
    const float* __restrict__ uw1,
    unsigned short* __restrict__ ew0s, unsigned short* __restrict__ ew1s,
    unsigned short* __restrict__ ew2s, unsigned short* __restrict__ w0as,
    unsigned short* __restrict__ w0bs, unsigned short* __restrict__ w1s_)
{
    const int bx = blockIdx.x, t = threadIdx.x;
    const float* srcW; int k0; unsigned short* dst;
    if (bx < 14)      { srcW = ew0; k0 = bx * 32;              dst = ew0s + bx * 8192; }
    else if (bx < 22) { srcW = ew1; k0 = (bx - 14) * 32;       dst = ew1s + (bx - 14) * 8192; }
    else if (bx < 30) { srcW = ew2; k0 = (bx - 22) * 32;       dst = ew2s + (bx - 22) * 8192; }
    else if (bx < 38) { srcW = uw0; k0 = (bx - 30) * 32;       dst = w0as + (bx - 30) * 8192; }
    else if (bx < 52) { srcW = uw0; k0 = 256 + (bx - 38) * 32; dst = w0bs + (bx - 38) * 8192; }
    else              { srcW = uw1; k0 = (bx - 52) * 32;       dst = w1s_ + (bx - 52) * 8192; }
    unsigned short v[32];
    #pragma unroll
    for (int kk = 0; kk < 32; ++kk) v[kk] = f2bf(srcW[(size_t)(k0 + kk) * kC + t]);
    #pragma unroll
    for (int j = 0; j < 4; ++j) *(short8*)(dst + t * 32 + j * 8) = *(short8*)(v + j * 8);
}

// ---------------------------------------------------------------------------
// 64-row-tile GEMM helper (used by main_mfma GEMM2). B-fragments straight
// from global chunked weights (L1/L2-hot).
// ---------------------------------------------------------------------------
__device__ __forceinline__ void gemm_x2_global(
    const unsigned short* __restrict__ x2e, const unsigned short* __restrict__ wsrc,
    int nchunk, int w, int q, int ml, float4v acc[4][4])
{
    const unsigned short* wp[4];
    #pragma unroll
    for (int ct = 0; ct < 4; ++ct) wp[ct] = wsrc + ((64 * w + 16 * ct + ml) * 32 + q * 8);
    for (int c = 0; c < nchunk; ++c) {
        short8 af[4], bfr[4];
        #pragma unroll
        for (int rt = 0; rt < 4; ++rt)
            af[rt] = *(const short8*)(x2e + (16 * rt + ml) * 264 + c * 32 + q * 8);
        #pragma unroll
        for (int ct = 0; ct < 4; ++ct) bfr[ct] = *(const short8*)(wp[ct] + c * 8192);
        #pragma unroll
        for (int rt = 0; rt < 4; ++rt)
            #pragma unroll
            for (int ct = 0; ct < 4; ++ct)
                acc[rt][ct] = __builtin_amdgcn_mfma_f32_16x16x32_bf16(af[rt], bfr[ct], acc[rt][ct], 0, 0, 0);
    }
}

// ---------------------------------------------------------------------------
// 16-row-tile GEMM helper for kernelA (1 row-tile x 4 col-tiles per wave).
// A-fragment row = ml, K-cols swept by chunks; B from global chunked weights.
// ---------------------------------------------------------------------------
__device__ __forceinline__ void gemm_x1_global(
    const unsigned short* __restrict__ x2e, const unsigned short* __restrict__ wsrc,
    int nchunk, int w, int q, int ml, float4v acc[4])
{
    const unsigned short* wp[4];
    #pragma unroll
    for (int ct = 0; ct < 4; ++ct) wp[ct] = wsrc + ((64 * w + 16 * ct + ml) * 32 + q * 8);
    for (int c = 0; c < nchunk; ++c) {
        short8 af = *(const short8*)(x2e + ml * 264 + c * 32 + q * 8);
        short8 bfr[4];
        #pragma unroll
        for (int ct = 0; ct < 4; ++ct) bfr[ct] = *(const short8*)(wp[ct] + c * 8192);
        #pragma unroll
        for (int ct = 0; ct < 4; ++ct)
            acc[ct] = __builtin_amdgcn_mfma_f32_16x16x32_bf16(af, bfr[ct], acc[ct], 0, 0, 0);
    }
}

// ---------------------------------------------------------------------------
// kernelA: 261 blocks.
//   bx 0..3   : hyper chains (launched first - longest serial latency)
//   bx 4      : iou mlp3
//   bx 5..260 : encoder mlp3, 16 rows each (256 blocks -> every CU busy),
//               fused with Z = src@W0a+b0 stored PERMUTED:
//               col (64w+16ct+ml) stored at (64w + 4*ml + ct) so main's
//               gather reads one ushort4 per (row,k) instead of 4x 2B.
// ---------------------------------------------------------------------------
__global__ __launch_bounds__(256) void kernelA(
    const float* __restrict__ pc, const float* __restrict__ dense,
    const unsigned short* __restrict__ ew0s, const float* __restrict__ eb0,
    const unsigned short* __restrict__ ew1s, const float* __restrict__ eb1,
    const unsigned short* __restrict__ ew2s, const float* __restrict__ eb2,
    const unsigned short* __restrict__ w0as, const float* __restrict__ ub0,
    const float* __restrict__ iou_token, const float* __restrict__ mask_tokens,
    const float* __restrict__ hw0, const float* __restrict__ hb0,
    const float* __restrict__ hw1, const float* __restrict__ hb1,
    const float* __restrict__ hw2, const float* __restrict__ hb2,
    const float* __restrict__ iw0, const float* __restrict__ ib0,
    const float* __restrict__ iw1, const float* __restrict__ ib1,
    const float* __restrict__ iw2, const float* __restrict__ ib2,
    unsigned short* __restrict__ Zbf,      // (B*NC, 256) bf16, PERMUTED cols
    float* __restrict__ hyper_out,         // (3, C)
    float* __restrict__ iou_out)           // (B, 3)
{
    __shared__ unsigned short x2e[16 * 264];   // 8448 B
    __shared__ float va[kC];
    __shared__ float vb[kC];
    const int tid = threadIdx.x, bx = blockIdx.x;

    if (bx >= 5) {
        const int row0 = (bx - 5) * 16;
        const int w = tid >> 6, lane = tid & 63, q = lane >> 4, ml = lane & 15;

        // ---- E0: 448 -> 256, relu ----
        const float* pcr = pc + (size_t)(row0 + ml) * kDIN;
        float4v acc0[4] = {};
        for (int c = 0; c < 14; ++c) {
            float4 f0 = *(const float4*)(pcr + c * 32 + q * 8);
            float4 f1 = *(const float4*)(pcr + c * 32 + q * 8 + 4);
            union { short8 s; unsigned int u[4]; } cv;
            cv.u[0] = pk_bf16(f0.x, f0.y); cv.u[1] = pk_bf16(f0.z, f0.w);
            cv.u[2] = pk_bf16(f1.x, f1.y); cv.u[3] = pk_bf16(f1.z, f1.w);
            short8 af = cv.s;
            #pragma unroll
            for (int ct = 0; ct < 4; ++ct) {
                short8 bfr = *(const short8*)(ew0s + (size_t)c * 8192 + (64 * w + 16 * ct + ml) * 32 + q * 8);
                acc0[ct] = __builtin_amdgcn_mfma_f32_16x16x32_bf16(af, bfr, acc0[ct], 0, 0, 0);
            }
        }
        {
            float bc[4];
            #pragma unroll
            for (int ct = 0; ct < 4; ++ct) bc[ct] = eb0[64 * w + 16 * ct + ml];
            #pragma unroll
            for (int i = 0; i < 4; ++i) {
                int row = 4 * q + i;
                #pragma unroll
                for (int ct = 0; ct < 4; ++ct)
                    x2e[row * 264 + 64 * w + 16 * ct + ml] = f2bf(fmaxf(acc0[ct][i] + bc[ct], 0.0f));
            }
        }
        __syncthreads();

        // ---- E1: 256 -> 256, relu ----
        float4v acc2[4] = {};
        gemm_x1_global(x2e, ew1s, 8, w, q, ml, acc2);
        __syncthreads();   // all reads of x2e done before overwrite
        {
            float bc[4];
            #pragma unroll
            for (int ct = 0; ct < 4; ++ct) bc[ct] = eb1[64 * w + 16 * ct + ml];
            #pragma unroll
            for (int i = 0; i < 4; ++i) {
                int row = 4 * q + i;
                #pragma unroll
                for (int ct = 0; ct < 4; ++ct)
                    x2e[row * 264 + 64 * w + 16 * ct + ml] = f2bf(fmaxf(acc2[ct][i] + bc[ct], 0.0f));
            }
        }
        __syncthreads();

        // ---- E2: 256 -> 256 (linear) + dense_prompt -> src ----
        float4v acc3[4] = {};
        gemm_x1_global(x2e, ew2s, 8, w, q, ml, acc3);
        __syncthreads();
        {
            float bc[4];
            #pragma unroll
            for (int ct = 0; ct < 4; ++ct) bc[ct] = eb2[64 * w + 16 * ct + ml];
            #pragma unroll
            for (int i = 0; i < 4; ++i) {
                int row = 4 * q + i;
                #pragma unroll
                for (int ct = 0; ct < 4; ++ct) {
                    int col = 64 * w + 16 * ct + ml;
                    float v = acc3[ct][i] + bc[ct] + dense[(size_t)(row0 + row) * kC + col];
                    x2e[row * 264 + col] = f2bf(v);
                }
            }
        }
        __syncthreads();

        // ---- EZ: Z = src @ W0a + up_b0 -> bf16 global (permuted cols) ----
        float4v accZ[4] = {};
        gemm_x1_global(x2e, w0as, 8, w, q, ml, accZ);
        {
            float bc[4];
            #pragma unroll
            for (int ct = 0; ct < 4; ++ct) bc[ct] = ub0[64 * w + 16 * ct + ml];
            #pragma unroll
            for (int i = 0; i < 4; ++i) {
                int row = 4 * q + i;
                ushort4v o;
                #pragma unroll
                for (int ct = 0; ct < 4; ++ct) o[ct] = f2bf(accZ[ct][i] + bc[ct]);
                *(ushort4v*)(Zbf + (size_t)(row0 + row) * kC + 64 * w + 4 * ml) = o;
            }
        }
    } else if (bx < 4) {
        const int m = bx;
        va[tid] = mask_tokens[m * kC + tid];
        __syncthreads();
        const float* W = hw0 + (size_t)m * kC * kC;
        float acc = hb0[m * kC + tid];
        for (int d = 0; d < kC; d++) acc = fmaf(va[d], W[d * kC + tid], acc);
        vb[tid] = fmaxf(acc, 0.0f);
        __syncthreads();
        W = hw1 + (size_t)m * kC * kC;
        acc = hb1[m * kC + tid];
        for (int d = 0; d < kC; d++) acc = fmaf(vb[d], W[d * kC + tid], acc);
        va[tid] = fmaxf(acc, 0.0f);
        __syncthreads();
        W = hw2 + (size_t)m * kC * kC;
        acc = hb2[m * kC + tid];
        for (int d = 0; d < kC; d++) acc = fmaf(va[d], W[d * kC + tid], acc);
        if (m >= 1) hyper_out[(m - 1) * kC + tid] = acc;
    } else {
        va[tid] = iou_token[tid];
        __syncthreads();
        float acc = ib0[tid];
        for (int d = 0; d < kC; d++) acc = fmaf(va[d], iw0[d * 256 + tid], acc);
        vb[tid] = fmaxf(acc, 0.0f);
        __syncthreads();
        acc = ib1[tid];
        for (int d = 0; d < 256; d++) acc = fmaf(vb[d], iw1[d * 256 + tid], acc);
        va[tid] = fmaxf(acc, 0.0f);
        __syncthreads();
        if (tid < kM) {
            acc = ib2[tid];
            for (int d = 0; d < 256; d++) acc = fmaf(va[d], iw2[d * kM + tid], acc);
            if (tid >= 1)
                for (int b = 0; b < kB; b++) iou_out[b * 3 + (tid - 1)] = acc;
        }
    }
}

// ---------------------------------------------------------------------------
// main: 64 rows x 256 cols per block. GEMM1 = pf@W0b (barrier-free, global
// frags) -> +interp via permuted-Z gather epilogue (ushort4 loads) -> LN ->
// GELU -> x2(LDS) -> GEMM2 (barrier-free) -> GELU -> hyper dots.
// ---------------------------------------------------------------------------
__global__ __launch_bounds__(256, 3) void main_mfma(
    const unsigned short* __restrict__ Zbf,
    const float* __restrict__ pf,
    const float* __restrict__ iwgt, const int* __restrict__ iidx,
    const unsigned short* __restrict__ w0bs, const unsigned short* __restrict__ w1s_,
    const float* __restrict__ lng, const float* __restrict__ lnb,
    const float* __restrict__ b1v, const float* __restrict__ hyper,
    float* __restrict__ masks)
{
    __shared__ unsigned short x2[64 * 264];     // 33792
    __shared__ int   gi[64][3];
    __shared__ float gw[64][3];
    __shared__ float sums[4][64];
    __shared__ float sqs[4][64];
    __shared__ float muA[64];
    __shared__ float rsA[64];
    __shared__ float pd[12][64];

    const int b = blockIdx.y, p0 = blockIdx.x * 64, tid = threadIdx.x;
    const int w = tid >> 6, lane = tid & 63, q = lane >> 4, ml = lane & 15;

    if (tid < 192) {
        int r = tid / 3, k = tid - r * 3;
        int base = (b * kNP + p0 + r) * 3 + k;
        gi[r][k] = iidx[base];
        gw[r][k] = iwgt[base];
    }
    __syncthreads();

    // ---------------- GEMM1: y = pf @ W0b (K=448, 14 chunks, NO barriers) ----
    const float* pfr[4];
    #pragma unroll
    for (int rt = 0; rt < 4; ++rt)
        pfr[rt] = pf + ((size_t)b * kNP + p0 + 16 * rt + ml) * kDIN;
    const unsigned short* wbp[4];
    #pragma unroll
    for (int ct = 0; ct < 4; ++ct) wbp[ct] = w0bs + ((64 * w + 16 * ct + ml) * 32 + q * 8);

    float4v acc[4][4] = {};
    for (int c = 0; c < 14; ++c) {
        short8 af[4], bfr[4];
        #pragma unroll
        for (int rt = 0; rt < 4; ++rt) {
            float4 f0 = *(const float4*)(pfr[rt] + c * 32 + q * 8);
            float4 f1 = *(const float4*)(pfr[rt] + c * 32 + q * 8 + 4);
            union { short8 s; unsigned int u[4]; } cv;
            cv.u[0] = pk_bf16(f0.x, f0.y); cv.u[1] = pk_bf16(f0.z, f0.w);
            cv.u[2] = pk_bf16(f1.x, f1.y); cv.u[3] = pk_bf16(f1.z, f1.w);
            af[rt] = cv.s;
        }
        #pragma unroll
        for (int ct = 0; ct < 4; ++ct) bfr[ct] = *(const short8*)(wbp[ct] + c * 8192);
        #pragma unroll
        for (int rt = 0; rt < 4; ++rt)
            #pragma unroll
            for (int ct = 0; ct < 4; ++ct)
                acc[rt][ct] = __builtin_amdgcn_mfma_f32_16x16x32_bf16(af[rt], bfr[ct], acc[rt][ct], 0, 0, 0);
    }

    // ------- interp add via permuted-Z gather (one ushort4 per row,k) -------
    {
        const unsigned short* zb = Zbf + (size_t)b * kNC * kC + 64 * w + 4 * ml;
        #pragma unroll
        for (int rt = 0; rt < 4; ++rt)
            #pragma unroll
            for (int i = 0; i < 4; ++i) {
                int row = 16 * rt + 4 * q + i;
                #pragma unroll
                for (int k = 0; k < 3; ++k) {
                    float wk = gw[row][k];
                    ushort4v z = *(const ushort4v*)(zb + (size_t)gi[row][k] * kC);
                    #pragma unroll
                    for (int ct = 0; ct < 4; ++ct)
                        acc[rt][ct][i] = fmaf(wk, bf2f(z[ct]), acc[rt][ct][i]);
                }
            }
    }

    // ---------------- LayerNorm stats ----------------
    {
        float s[4][4], s2[4][4];
        #pragma unroll
        for (int rt = 0; rt < 4; ++rt)
            #pragma unroll
            for (int i = 0; i < 4; ++i) {
                float a = 0.f, b2 = 0.f;
                #pragma unroll
                for (int ct = 0; ct < 4; ++ct) {
                    float v = acc[rt][ct][i];
                    a += v; b2 = fmaf(v, v, b2);
                }
                s[rt][i] = a; s2[rt][i] = b2;
            }
        #pragma unroll
        for (int o = 1; o < 16; o <<= 1) {
            #pragma unroll
            for (int rt = 0; rt < 4; ++rt)
                #pragma unroll
                for (int i = 0; i < 4; ++i) {
                    s[rt][i]  += __shfl_xor(s[rt][i], o);
                    s2[rt][i] += __shfl_xor(s2[rt][i], o);
                }
        }
        if (ml == 0) {
            #pragma unroll
            for (int rt = 0; rt < 4; ++rt)
                #pragma unroll
                for (int i = 0; i < 4; ++i) {
                    int row = 16 * rt + 4 * q + i;
                    sums[w][row] = s[rt][i];
                    sqs[w][row]  = s2[rt][i];
                }
        }
    }
    __syncthreads();
    if (tid < 64) {
        float ts = sums[0][tid] + sums[1][tid] + sums[2][tid] + sums[3][tid];
        float tq = sqs[0][tid] + sqs[1][tid] + sqs[2][tid] + sqs[3][tid];
        float mu = ts * (1.0f / 256.0f);
        float var = tq * (1.0f / 256.0f) - mu * mu;
        muA[tid] = mu;
        rsA[tid] = rsqrtf(var + 1e-5f);
    }
    __syncthreads();

    // ---------------- normalize + GELU -> x2 (bf16, LDS) ----------------
    {
        float gc[4], oc[4];
        #pragma unroll
        for (int ct = 0; ct < 4; ++ct) {
            gc[ct] = lng[64 * w + 16 * ct + ml];
            oc[ct] = lnb[64 * w + 16 * ct + ml];
        }
        #pragma unroll
        for (int rt = 0; rt < 4; ++rt)
            #pragma unroll
            for (int i = 0; i < 4; ++i) {
                int row = 16 * rt + 4 * q + i;
                float mu = muA[row], rs = rsA[row];
                #pragma unroll
                for (int ct = 0; ct < 4; ++ct) {
                    float v = (acc[rt][ct][i] - mu) * rs * gc[ct] + oc[ct];
                    x2[row * 264 + 64 * w + 16 * ct + ml] = f2bf(gelu_exact(v));
                }
            }
    }
    __syncthreads();

    // ---------------- GEMM2: K=256, 8 chunks, NO barriers ----------------
    float4v acc2[4][4] = {};
    gemm_x2_global(x2, w1s_, 8, w, q, ml, acc2);

    // ---------------- GELU + hyper partial dots ----------------
    {
        float bc1[4], hy[3][4];
        #pragma unroll
        for (int ct = 0; ct < 4; ++ct) bc1[ct] = b1v[64 * w + 16 * ct + ml];
        #pragma unroll
        for (int m = 0; m < 3; ++m)
            #pragma unroll
            for (int ct = 0; ct < 4; ++ct) hy[m][ct] = hyper[m * kC + 64 * w + 16 * ct + ml];
        float pdl[3][4][4] = {};
        #pragma unroll
        for (int rt = 0; rt < 4; ++rt)
            #pragma unroll
            for (int ct = 0; ct < 4; ++ct)
                #pragma unroll
                for (int i = 0; i < 4; ++i) {
                    float u = gelu_exact(acc2[rt][ct][i] + bc1[ct]);
                    #pragma unroll
                    for (int m = 0; m < 3; ++m) pdl[m][rt][i] = fmaf(u, hy[m][ct], pdl[m][rt][i]);
                }
        #pragma unroll
        for (int o = 1; o < 16; o <<= 1) {
            #pragma unroll
            for (int m = 0; m < 3; ++m)
                #pragma unroll
                for (int rt = 0; rt < 4; ++rt)
                    #pragma unroll
                    for (int i = 0; i < 4; ++i)
                        pdl[m][rt][i] += __shfl_xor(pdl[m][rt][i], o);
        }
        if (ml < 3) {
            const int m = ml;
            #pragma unroll
            for (int rt = 0; rt < 4; ++rt)
                #pragma unroll
                for (int i = 0; i < 4; ++i)
                    pd[w * 3 + m][16 * rt + 4 * q + i] = pdl[m][rt][i];
        }
    }
    __syncthreads();
    if (tid < 192) {
        int m = tid >> 6, r = tid & 63;
        float v = pd[0 + m][r] + pd[3 + m][r] + pd[6 + m][r] + pd[9 + m][r];
        masks[((size_t)b * 3 + m) * kNP + p0 + r] = v;
    }
}

// ---------------------------------------------------------------------------
extern "C" void kernel_launch(void* const* d_in, const int* in_sizes, int n_in,
                              void* d_out, int out_size, void* d_ws, size_t ws_size,
                              hipStream_t stream) {
    const float* pc_emb  = (const float*)d_in[0];
    const float* dense   = (const float*)d_in[3];
    const float* pf      = (const float*)d_in[4];
    const float* iwgt    = (const float*)d_in[5];
    const int*   iidx    = (const int*)d_in[6];
    const float* iou_tok = (const float*)d_in[7];
    const float* mtok    = (const float*)d_in[8];
    const float* ew0 = (const float*)d_in[9];
    const float* eb0 = (const float*)d_in[10];
    const float* ew1 = (const float*)d_in[11];
    const float* eb1 = (const float*)d_in[12];
    const float* ew2 = (const float*)d_in[13];
    const float* eb2 = (const float*)d_in[14];
    const float* uw0 = (const float*)d_in[15];
    const float* ub0 = (const float*)d_in[16];
    const float* lng = (const float*)d_in[17];
    const float* lnb = (const float*)d_in[18];
    const float* uw1 = (const float*)d_in[19];
    const float* ub1 = (const float*)d_in[20];
    const float* hw0 = (const float*)d_in[21];
    const float* hb0 = (const float*)d_in[22];
    const float* hw1 = (const float*)d_in[23];
    const float* hb1 = (const float*)d_in[24];
    const float* hw2 = (const float*)d_in[25];
    const float* hb2 = (const float*)d_in[26];
    const float* iw0 = (const float*)d_in[27];
    const float* ib0 = (const float*)d_in[28];
    const float* iw1 = (const float*)d_in[29];
    const float* ib1 = (const float*)d_in[30];
    const float* iw2 = (const float*)d_in[31];
    const float* ib2 = (const float*)d_in[32];

    float* out = (float*)d_out;   // masks (4,3,32768) then iou (4,3)

    // workspace layout (bytes)
    char* ws = (char*)d_ws;
    unsigned short* Zbf  = (unsigned short*)(ws + 0);        // 2,097,152
    float* ws_hyper      = (float*)(ws + 2097152);           // 3,072
    unsigned short* ew0s = (unsigned short*)(ws + 2100224);  // 229,376
    unsigned short* ew1s = (unsigned short*)(ws + 2329600);  // 131,072
    unsigned short* ew2s = (unsigned short*)(ws + 2460672);  // 131,072
    unsigned short* w0as = (unsigned short*)(ws + 2591744);  // 131,072
    unsigned short* w0bs = (unsigned short*)(ws + 2722816);  // 229,376
    unsigned short* w1s_ = (unsigned short*)(ws + 2952192);  // 131,072

    prep_weights<<<60, 256, 0, stream>>>(ew0, ew1, ew2, uw0, uw1,
                                         ew0s, ew1s, ew2s, w0as, w0bs, w1s_);

    kernelA<<<261, 256, 0, stream>>>(
        pc_emb, dense, ew0s, eb0, ew1s, eb1, ew2s, eb2, w0as, ub0,
        iou_tok, mtok, hw0, hb0, hw1, hb1, hw2, hb2,
        iw0, ib0, iw1, ib1, iw2, ib2,
        Zbf, ws_hyper, out + (size_t)kB * 3 * kNP);

    main_mfma<<<dim3(kNP / 64, kB), 256, 0, stream>>>(
        Zbf, pf, iwgt, iidx, w0bs, w1s_,
        lng, lnb, ub1, ws_hyper, out);
}

// Round 5
// 615.723 us; speedup vs baseline: 1.0376x; 1.0360x over previous
//
#include <hip/hip_runtime.h>
#include <hip/hip_bf16.h>
#include <math.h>

constexpr int kB   = 4;
constexpr int kNC  = 1024;
constexpr int kNP  = 32768;
constexpr int kC   = 256;
constexpr int kDIN = 448;
constexpr int kM   = 4;

typedef __attribute__((ext_vector_type(8))) short short8;
typedef __attribute__((ext_vector_type(4))) float float4v;
typedef __attribute__((ext_vector_type(4))) unsigned short ushort4v;

__device__ __forceinline__ float gelu_exact(float x) {
    return 0.5f * x * (1.0f + erff(x * 0.70710678118654752440f));
}
__device__ __forceinline__ unsigned short f2bf(float f) {
    unsigned int u = __float_as_uint(f);
    unsigned int r = (u + 0x7fffu + ((u >> 16) & 1u)) >> 16;
    return (unsigned short)r;
}
__device__ __forceinline__ float bf2f(unsigned short s) {
    return __uint_as_float(((unsigned int)s) << 16);
}
// packed f32x2 -> bf16x2 (v_cvt_pk_bf16_f32 on gfx950 via hip_bf16)
__device__ __forceinline__ unsigned int pk_bf16(float lo, float hi) {
    __hip_bfloat162 h = __float22bfloat162_rn(float2{lo, hi});
    union { __hip_bfloat162 h; unsigned int u; } c;
    c.h = h;
    return c.u;
}

// ---------------------------------------------------------------------------
// prep: convert weights to bf16 chunked layout ws[c][n][kk], n in [0,256),
// kk in [0,32). Coalesced reads (256 threads sweep n for each k-row).
// 60 blocks: ew0(14) ew1(8) ew2(8) W0a(8) W0b(14) uw1(8)
// ---------------------------------------------------------------------------
__global__ __launch_bounds__(256) void prep_weights(
    const float* __restrict__ ew0, const float* __restrict__ ew1,
    const float* __restrict__ ew2, const float* __restrict__ uw0,
    const float* __restrict__ uw1,
    unsigned short* __restrict__ ew0s, unsigned short* __restrict__ ew1s,
    unsigned short* __restrict__ ew2s, unsigned short* __restrict__ w0as,
    unsigned short* __restrict__ w0bs, unsigned short* __restrict__ w1s_)
{
    const int bx = blockIdx.x, t = threadIdx.x;
    const float* srcW; int k0; unsigned short* dst;
    if (bx < 14)      { srcW = ew0; k0 = bx * 32;              dst = ew0s + bx * 8192; }
    else if (bx < 22) { srcW = ew1; k0 = (bx - 14) * 32;       dst = ew1s + (bx - 14) * 8192; }
    else if (bx < 30) { srcW = ew2; k0 = (bx - 22) * 32;       dst = ew2s + (bx - 22) * 8192; }
    else if (bx < 38) { srcW = uw0; k0 = (bx - 30) * 32;       dst = w0as + (bx - 30) * 8192; }
    else if (bx < 52) { srcW = uw0; k0 = 256 + (bx - 38) * 32; dst = w0bs + (bx - 38) * 8192; }
    else              { srcW = uw1; k0 = (bx - 52) * 32;       dst = w1s_ + (bx - 52) * 8192; }
    unsigned short v[32];
    #pragma unroll
    for (int kk = 0; kk < 32; ++kk) v[kk] = f2bf(srcW[(size_t)(k0 + kk) * kC + t]);
    #pragma unroll
    for (int j = 0; j < 4; ++j) *(short8*)(dst + t * 32 + j * 8) = *(short8*)(v + j * 8);
}

// ---------------------------------------------------------------------------
// 64-row-tile GEMM helper (x2 LDS, stride 264). B-fragments straight from
// global chunked weights (L1/L2-hot).
// ---------------------------------------------------------------------------
__device__ __forceinline__ void gemm_x2_global(
    const unsigned short* __restrict__ x2e, const unsigned short* __restrict__ wsrc,
    int nchunk, int w, int q, int ml, float4v acc[4][4])
{
    const unsigned short* wp[4];
    #pragma unroll
    for (int ct = 0; ct < 4; ++ct) wp[ct] = wsrc + ((64 * w + 16 * ct + ml) * 32 + q * 8);
    for (int c = 0; c < nchunk; ++c) {
        short8 af[4], bfr[4];
        #pragma unroll
        for (int rt = 0; rt < 4; ++rt)
            af[rt] = *(const short8*)(x2e + (16 * rt + ml) * 264 + c * 32 + q * 8);
        #pragma unroll
        for (int ct = 0; ct < 4; ++ct) bfr[ct] = *(const short8*)(wp[ct] + c * 8192);
        #pragma unroll
        for (int rt = 0; rt < 4; ++rt)
            #pragma unroll
            for (int ct = 0; ct < 4; ++ct)
                acc[rt][ct] = __builtin_amdgcn_mfma_f32_16x16x32_bf16(af[rt], bfr[ct], acc[rt][ct], 0, 0, 0);
    }
}

// ---------------------------------------------------------------------------
// 16-row-tile GEMM helper for kernelA (1 row-tile x 4 col-tiles per wave).
// ---------------------------------------------------------------------------
__device__ __forceinline__ void gemm_x1_global(
    const unsigned short* __restrict__ x2e, const unsigned short* __restrict__ wsrc,
    int nchunk, int w, int q, int ml, float4v acc[4])
{
    const unsigned short* wp[4];
    #pragma unroll
    for (int ct = 0; ct < 4; ++ct) wp[ct] = wsrc + ((64 * w + 16 * ct + ml) * 32 + q * 8);
    for (int c = 0; c < nchunk; ++c) {
        short8 af = *(const short8*)(x2e + ml * 264 + c * 32 + q * 8);
        short8 bfr[4];
        #pragma unroll
        for (int ct = 0; ct < 4; ++ct) bfr[ct] = *(const short8*)(wp[ct] + c * 8192);
        #pragma unroll
        for (int ct = 0; ct < 4; ++ct)
            acc[ct] = __builtin_amdgcn_mfma_f32_16x16x32_bf16(af, bfr[ct], acc[ct], 0, 0, 0);
    }
}

// ---------------------------------------------------------------------------
// kernelA: 261 blocks.
//   bx 0..3   : hyper chains; bx 4: iou mlp3; bx 5..260: encoder, 16 rows each
//   Z stored PERMUTED: col (64w+16ct+ml) at (64w + 4*ml + ct).
// ---------------------------------------------------------------------------
__global__ __launch_bounds__(256) void kernelA(
    const float* __restrict__ pc, const float* __restrict__ dense,
    const unsigned short* __restrict__ ew0s, const float* __restrict__ eb0,
    const unsigned short* __restrict__ ew1s, const float* __restrict__ eb1,
    const unsigned short* __restrict__ ew2s, const float* __restrict__ eb2,
    const unsigned short* __restrict__ w0as, const float* __restrict__ ub0,
    const float* __restrict__ iou_token, const float* __restrict__ mask_tokens,
    const float* __restrict__ hw0, const float* __restrict__ hb0,
    const float* __restrict__ hw1, const float* __restrict__ hb1,
    const float* __restrict__ hw2, const float* __restrict__ hb2,
    const float* __restrict__ iw0, const float* __restrict__ ib0,
    const float* __restrict__ iw1, const float* __restrict__ ib1,
    const float* __restrict__ iw2, const float* __restrict__ ib2,
    unsigned short* __restrict__ Zbf,      // (B*NC, 256) bf16, PERMUTED cols
    float* __restrict__ hyper_out,         // (3, C)
    float* __restrict__ iou_out)           // (B, 3)
{
    __shared__ unsigned short x2e[16 * 264];   // 8448 B
    __shared__ float va[kC];
    __shared__ float vb[kC];
    const int tid = threadIdx.x, bx = blockIdx.x;

    if (bx >= 5) {
        const int row0 = (bx - 5) * 16;
        const int w = tid >> 6, lane = tid & 63, q = lane >> 4, ml = lane & 15;

        // ---- E0: 448 -> 256, relu ----
        const float* pcr = pc + (size_t)(row0 + ml) * kDIN;
        float4v acc0[4] = {};
        for (int c = 0; c < 14; ++c) {
            float4 f0 = *(const float4*)(pcr + c * 32 + q * 8);
            float4 f1 = *(const float4*)(pcr + c * 32 + q * 8 + 4);
            union { short8 s; unsigned int u[4]; } cv;
            cv.u[0] = pk_bf16(f0.x, f0.y); cv.u[1] = pk_bf16(f0.z, f0.w);
            cv.u[2] = pk_bf16(f1.x, f1.y); cv.u[3] = pk_bf16(f1.z, f1.w);
            short8 af = cv.s;
            #pragma unroll
            for (int ct = 0; ct < 4; ++ct) {
                short8 bfr = *(const short8*)(ew0s + (size_t)c * 8192 + (64 * w + 16 * ct + ml) * 32 + q * 8);
                acc0[ct] = __builtin_amdgcn_mfma_f32_16x16x32_bf16(af, bfr, acc0[ct], 0, 0, 0);
            }
        }
        {
            float bc[4];
            #pragma unroll
            for (int ct = 0; ct < 4; ++ct) bc[ct] = eb0[64 * w + 16 * ct + ml];
            #pragma unroll
            for (int i = 0; i < 4; ++i) {
                int row = 4 * q + i;
                #pragma unroll
                for (int ct = 0; ct < 4; ++ct)
                    x2e[row * 264 + 64 * w + 16 * ct + ml] = f2bf(fmaxf(acc0[ct][i] + bc[ct], 0.0f));
            }
        }
        __syncthreads();

        // ---- E1: 256 -> 256, relu ----
        float4v acc2[4] = {};
        gemm_x1_global(x2e, ew1s, 8, w, q, ml, acc2);
        __syncthreads();
        {
            float bc[4];
            #pragma unroll
            for (int ct = 0; ct < 4; ++ct) bc[ct] = eb1[64 * w + 16 * ct + ml];
            #pragma unroll
            for (int i = 0; i < 4; ++i) {
                int row = 4 * q + i;
                #pragma unroll
                for (int ct = 0; ct < 4; ++ct)
                    x2e[row * 264 + 64 * w + 16 * ct + ml] = f2bf(fmaxf(acc2[ct][i] + bc[ct], 0.0f));
            }
        }
        __syncthreads();

        // ---- E2: 256 -> 256 (linear) + dense_prompt -> src ----
        float4v acc3[4] = {};
        gemm_x1_global(x2e, ew2s, 8, w, q, ml, acc3);
        __syncthreads();
        {
            float bc[4];
            #pragma unroll
            for (int ct = 0; ct < 4; ++ct) bc[ct] = eb2[64 * w + 16 * ct + ml];
            #pragma unroll
            for (int i = 0; i < 4; ++i) {
                int row = 4 * q + i;
                #pragma unroll
                for (int ct = 0; ct < 4; ++ct) {
                    int col = 64 * w + 16 * ct + ml;
                    float v = acc3[ct][i] + bc[ct] + dense[(size_t)(row0 + row) * kC + col];
                    x2e[row * 264 + col] = f2bf(v);
                }
            }
        }
        __syncthreads();

        // ---- EZ: Z = src @ W0a + up_b0 -> bf16 global (permuted cols) ----
        float4v accZ[4] = {};
        gemm_x1_global(x2e, w0as, 8, w, q, ml, accZ);
        {
            float bc[4];
            #pragma unroll
            for (int ct = 0; ct < 4; ++ct) bc[ct] = ub0[64 * w + 16 * ct + ml];
            #pragma unroll
            for (int i = 0; i < 4; ++i) {
                int row = 4 * q + i;
                ushort4v o;
                #pragma unroll
                for (int ct = 0; ct < 4; ++ct) o[ct] = f2bf(accZ[ct][i] + bc[ct]);
                *(ushort4v*)(Zbf + (size_t)(row0 + row) * kC + 64 * w + 4 * ml) = o;
            }
        }
    } else if (bx < 4) {
        const int m = bx;
        va[tid] = mask_tokens[m * kC + tid];
        __syncthreads();
        const float* W = hw0 + (size_t)m * kC * kC;
        float acc = hb0[m * kC + tid];
        for (int d = 0; d < kC; d++) acc = fmaf(va[d], W[d * kC + tid], acc);
        vb[tid] = fmaxf(acc, 0.0f);
        __syncthreads();
        W = hw1 + (size_t)m * kC * kC;
        acc = hb1[m * kC + tid];
        for (int d = 0; d < kC; d++) acc = fmaf(vb[d], W[d * kC + tid], acc);
        va[tid] = fmaxf(acc, 0.0f);
        __syncthreads();
        W = hw2 + (size_t)m * kC * kC;
        acc = hb2[m * kC + tid];
        for (int d = 0; d < kC; d++) acc = fmaf(va[d], W[d * kC + tid], acc);
        if (m >= 1) hyper_out[(m - 1) * kC + tid] = acc;
    } else {
        va[tid] = iou_token[tid];
        __syncthreads();
        float acc = ib0[tid];
        for (int d = 0; d < kC; d++) acc = fmaf(va[d], iw0[d * 256 + tid], acc);
        vb[tid] = fmaxf(acc, 0.0f);
        __syncthreads();
        acc = ib1[tid];
        for (int d = 0; d < 256; d++) acc = fmaf(vb[d], iw1[d * 256 + tid], acc);
        va[tid] = fmaxf(acc, 0.0f);
        __syncthreads();
        if (tid < kM) {
            acc = ib2[tid];
            for (int d = 0; d < 256; d++) acc = fmaf(va[d], iw2[d * kM + tid], acc);
            if (tid >= 1)
                for (int b = 0; b < kB; b++) iou_out[b * 3 + (tid - 1)] = acc;
        }
    }
}

// ---------------------------------------------------------------------------
// main: 64 rows x 256 cols per block.
// pf tile cooperatively staged to LDS as bf16 (two K=224 halves, stride 232,
// reusing the x2 buffer) -> GEMM1 reads ds_read_b128. Kills the 4x per-wave
// duplicate pf loads + 4x cvt_pk packing.
// ---------------------------------------------------------------------------
__global__ __launch_bounds__(256, 3) void main_mfma(
    const unsigned short* __restrict__ Zbf,
    const float* __restrict__ pf,
    const float* __restrict__ iwgt, const int* __restrict__ iidx,
    const unsigned short* __restrict__ w0bs, const unsigned short* __restrict__ w1s_,
    const float* __restrict__ lng, const float* __restrict__ lnb,
    const float* __restrict__ b1v, const float* __restrict__ hyper,
    float* __restrict__ masks)
{
    __shared__ unsigned short buf[64 * 264];    // 33792 B: pf halves (stride 232) then x2 (stride 264)
    __shared__ int   gi[64][3];
    __shared__ float gw[64][3];
    __shared__ float sums[4][64];
    __shared__ float sqs[4][64];
    __shared__ float muA[64];
    __shared__ float rsA[64];
    __shared__ float pd[12][64];

    const int b = blockIdx.y, p0 = blockIdx.x * 64, tid = threadIdx.x;
    const int w = tid >> 6, lane = tid & 63, q = lane >> 4, ml = lane & 15;

    if (tid < 192) {
        int r = tid / 3, k = tid - r * 3;
        int base = (b * kNP + p0 + r) * 3 + k;
        gi[r][k] = iidx[base];
        gw[r][k] = iwgt[base];
    }

    float4v acc[4][4] = {};
    const float* pfb = pf + ((size_t)b * kNP + p0) * kDIN;

    // ---------------- GEMM1: y = pf @ W0b, two K=224 halves via LDS ---------
    #pragma unroll
    for (int h = 0; h < 2; ++h) {
        // stage: 64 rows x 224 cols f32 -> bf16, stride 232 (16B-aligned rows)
        #pragma unroll
        for (int j = 0; j < 7; ++j) {
            int idx = j * 256 + tid;          // 0..1791 ; 28 short8 per row-half
            int r = idx / 28;
            int co = idx - r * 28;
            const float* g = pfb + (size_t)r * kDIN + h * 224 + co * 8;
            float4 f0 = *(const float4*)g;
            float4 f1 = *(const float4*)(g + 4);
            union { short8 s; unsigned int u[4]; } cv;
            cv.u[0] = pk_bf16(f0.x, f0.y); cv.u[1] = pk_bf16(f0.z, f0.w);
            cv.u[2] = pk_bf16(f1.x, f1.y); cv.u[3] = pk_bf16(f1.z, f1.w);
            *(short8*)&buf[r * 232 + co * 8] = cv.s;
        }
        __syncthreads();
        // fragment base: (64*w + 16*ct + ml)*32 + q*8 = 2048w + 512ct + 32ml + 8q
        const unsigned short* wh = w0bs + (size_t)h * 7 * 8192 + ((64 * w + ml) * 32 + q * 8);
        for (int c = 0; c < 7; ++c) {
            short8 af[4], bfr[4];
            #pragma unroll
            for (int rt = 0; rt < 4; ++rt)
                af[rt] = *(const short8*)&buf[(16 * rt + ml) * 232 + c * 32 + q * 8];
            #pragma unroll
            for (int ct = 0; ct < 4; ++ct)
                bfr[ct] = *(const short8*)(wh + (size_t)c * 8192 + 512 * ct);
            #pragma unroll
            for (int rt = 0; rt < 4; ++rt)
                #pragma unroll
                for (int ct = 0; ct < 4; ++ct)
                    acc[rt][ct] = __builtin_amdgcn_mfma_f32_16x16x32_bf16(af[rt], bfr[ct], acc[rt][ct], 0, 0, 0);
        }
        __syncthreads();   // pf half consumed before restage/overwrite
    }

    // ------- interp add via permuted-Z gather (one ushort4 per row,k) -------
    {
        const unsigned short* zb = Zbf + (size_t)b * kNC * kC + 64 * w + 4 * ml;
        #pragma unroll
        for (int rt = 0; rt < 4; ++rt)
            #pragma unroll
            for (int i = 0; i < 4; ++i) {
                int row = 16 * rt + 4 * q + i;
                #pragma unroll
                for (int k = 0; k < 3; ++k) {
                    float wk = gw[row][k];
                    ushort4v z = *(const ushort4v*)(zb + (size_t)gi[row][k] * kC);
                    #pragma unroll
                    for (int ct = 0; ct < 4; ++ct)
                        acc[rt][ct][i] = fmaf(wk, bf2f(z[ct]), acc[rt][ct][i]);
                }
            }
    }

    // ---------------- LayerNorm stats ----------------
    {
        float s[4][4], s2[4][4];
        #pragma unroll
        for (int rt = 0; rt < 4; ++rt)
            #pragma unroll
            for (int i = 0; i < 4; ++i) {
                float a = 0.f, b2 = 0.f;
                #pragma unroll
                for (int ct = 0; ct < 4; ++ct) {
                    float v = acc[rt][ct][i];
                    a += v; b2 = fmaf(v, v, b2);
                }
                s[rt][i] = a; s2[rt][i] = b2;
            }
        #pragma unroll
        for (int o = 1; o < 16; o <<= 1) {
            #pragma unroll
            for (int rt = 0; rt < 4; ++rt)
                #pragma unroll
                for (int i = 0; i < 4; ++i) {
                    s[rt][i]  += __shfl_xor(s[rt][i], o);
                    s2[rt][i] += __shfl_xor(s2[rt][i], o);
                }
        }
        if (ml == 0) {
            #pragma unroll
            for (int rt = 0; rt < 4; ++rt)
                #pragma unroll
                for (int i = 0; i < 4; ++i) {
                    int row = 16 * rt + 4 * q + i;
                    sums[w][row] = s[rt][i];
                    sqs[w][row]  = s2[rt][i];
                }
        }
    }
    __syncthreads();
    if (tid < 64) {
        float ts = sums[0][tid] + sums[1][tid] + sums[2][tid] + sums[3][tid];
        float tq = sqs[0][tid] + sqs[1][tid] + sqs[2][tid] + sqs[3][tid];
        float mu = ts * (1.0f / 256.0f);
        float var = tq * (1.0f / 256.0f) - mu * mu;
        muA[tid] = mu;
        rsA[tid] = rsqrtf(var + 1e-5f);
    }
    __syncthreads();

    // ---------------- normalize + GELU -> x2 (bf16, LDS stride 264) --------
    {
        float gc[4], oc[4];
        #pragma unroll
        for (int ct = 0; ct < 4; ++ct) {
            gc[ct] = lng[64 * w + 16 * ct + ml];
            oc[ct] = lnb[64 * w + 16 * ct + ml];
        }
        #pragma unroll
        for (int rt = 0; rt < 4; ++rt)
            #pragma unroll
            for (int i = 0; i < 4; ++i) {
                int row = 16 * rt + 4 * q + i;
                float mu = muA[row], rs = rsA[row];
                #pragma unroll
                for (int ct = 0; ct < 4; ++ct) {
                    float v = (acc[rt][ct][i] - mu) * rs * gc[ct] + oc[ct];
                    buf[row * 264 + 64 * w + 16 * ct + ml] = f2bf(gelu_exact(v));
                }
            }
    }
    __syncthreads();

    // ---------------- GEMM2: K=256, 8 chunks, NO barriers ----------------
    float4v acc2[4][4] = {};
    gemm_x2_global(buf, w1s_, 8, w, q, ml, acc2);

    // ---------------- GELU + hyper partial dots ----------------
    {
        float bc1[4], hy[3][4];
        #pragma unroll
        for (int ct = 0; ct < 4; ++ct) bc1[ct] = b1v[64 * w + 16 * ct + ml];
        #pragma unroll
        for (int m = 0; m < 3; ++m)
            #pragma unroll
            for (int ct = 0; ct < 4; ++ct) hy[m][ct] = hyper[m * kC + 64 * w + 16 * ct + ml];
        float pdl[3][4][4] = {};
        #pragma unroll
        for (int rt = 0; rt < 4; ++rt)
            #pragma unroll
            for (int ct = 0; ct < 4; ++ct)
                #pragma unroll
                for (int i = 0; i < 4; ++i) {
                    float u = gelu_exact(acc2[rt][ct][i] + bc1[ct]);
                    #pragma unroll
                    for (int m = 0; m < 3; ++m) pdl[m][rt][i] = fmaf(u, hy[m][ct], pdl[m][rt][i]);
                }
        #pragma unroll
        for (int o = 1; o < 16; o <<= 1) {
            #pragma unroll
            for (int m = 0; m < 3; ++m)
                #pragma unroll
                for (int rt = 0; rt < 4; ++rt)
                    #pragma unroll
                    for (int i = 0; i < 4; ++i)
                        pdl[m][rt][i] += __shfl_xor(pdl[m][rt][i], o);
        }
        if (ml < 3) {
            const int m = ml;
            #pragma unroll
            for (int rt = 0; rt < 4; ++rt)
                #pragma unroll
                for (int i = 0; i < 4; ++i)
                    pd[w * 3 + m][16 * rt + 4 * q + i] = pdl[m][rt][i];
        }
    }
    __syncthreads();
    if (tid < 192) {
        int m = tid >> 6, r = tid & 63;
        float v = pd[0 + m][r] + pd[3 + m][r] + pd[6 + m][r] + pd[9 + m][r];
        masks[((size_t)b * 3 + m) * kNP + p0 + r] = v;
    }
}

// ---------------------------------------------------------------------------
extern "C" void kernel_launch(void* const* d_in, const int* in_sizes, int n_in,
                              void* d_out, int out_size, void* d_ws, size_t ws_size,
                              hipStream_t stream) {
    const float* pc_emb  = (const float*)d_in[0];
    const float* dense   = (const float*)d_in[3];
    const float* pf      = (const float*)d_in[4];
    const float* iwgt    = (const float*)d_in[5];
    const int*   iidx    = (const int*)d_in[6];
    const float* iou_tok = (const float*)d_in[7];
    const float* mtok    = (const float*)d_in[8];
    const float* ew0 = (const float*)d_in[9];
    const float* eb0 = (const float*)d_in[10];
    const float* ew1 = (const float*)d_in[11];
    const float* eb1 = (const float*)d_in[12];
    const float* ew2 = (const float*)d_in[13];
    const float* eb2 = (const float*)d_in[14];
    const float* uw0 = (const float*)d_in[15];
    const float* ub0 = (const float*)d_in[16];
    const float* lng = (const float*)d_in[17];
    const float* lnb = (const float*)d_in[18];
    const float* uw1 = (const float*)d_in[19];
    const float* ub1 = (const float*)d_in[20];
    const float* hw0 = (const float*)d_in[21];
    const float* hb0 = (const float*)d_in[22];
    const float* hw1 = (const float*)d_in[23];
    const float* hb1 = (const float*)d_in[24];
    const float* hw2 = (const float*)d_in[25];
    const float* hb2 = (const float*)d_in[26];
    const float* iw0 = (const float*)d_in[27];
    const float* ib0 = (const float*)d_in[28];
    const float* iw1 = (const float*)d_in[29];
    const float* ib1 = (const float*)d_in[30];
    const float* iw2 = (const float*)d_in[31];
    const float* ib2 = (const float*)d_in[32];

    float* out = (float*)d_out;   // masks (4,3,32768) then iou (4,3)

    // workspace layout (bytes)
    char* ws = (char*)d_ws;
    unsigned short* Zbf  = (unsigned short*)(ws + 0);        // 2,097,152
    float* ws_hyper      = (float*)(ws + 2097152);           // 3,072
    unsigned short* ew0s = (unsigned short*)(ws + 2100224);  // 229,376
    unsigned short* ew1s = (unsigned short*)(ws + 2329600);  // 131,072
    unsigned short* ew2s = (unsigned short*)(ws + 2460672);  // 131,072
    unsigned short* w0as = (unsigned short*)(ws + 2591744);  // 131,072
    unsigned short* w0bs = (unsigned short*)(ws + 2722816);  // 229,376
    unsigned short* w1s_ = (unsigned short*)(ws + 2952192);  // 131,072

    prep_weights<<<60, 256, 0, stream>>>(ew0, ew1, ew2, uw0, uw1,
                                         ew0s, ew1s, ew2s, w0as, w0bs, w1s_);

    kernelA<<<261, 256, 0, stream>>>(
        pc_emb, dense, ew0s, eb0, ew1s, eb1, ew2s, eb2, w0as, ub0,
        iou_tok, mtok, hw0, hb0, hw1, hb1, hw2, hb2,
        iw0, ib0, iw1, ib1, iw2, ib2,
        Zbf, ws_hyper, out + (size_t)kB * 3 * kNP);

    main_mfma<<<dim3(kNP / 64, kB), 256, 0, stream>>>(
        Zbf, pf, iwgt, iidx, w0bs, w1s_,
        lng, lnb, ub1, ws_hyper, out);
}

// Round 6
// 544.413 us; speedup vs baseline: 1.1735x; 1.1310x over previous
//
#include <hip/hip_runtime.h>
#include <hip/hip_bf16.h>
#include <math.h>

constexpr int kB   = 4;
constexpr int kNC  = 1024;
constexpr int kNP  = 32768;
constexpr int kC   = 256;
constexpr int kDIN = 448;
constexpr int kM   = 4;

typedef __attribute__((ext_vector_type(8))) short short8;
typedef __attribute__((ext_vector_type(4))) float float4v;
typedef __attribute__((ext_vector_type(4))) unsigned short ushort4v;

__device__ __forceinline__ float gelu_exact(float x) {
    return 0.5f * x * (1.0f + erff(x * 0.70710678118654752440f));
}
__device__ __forceinline__ unsigned short f2bf(float f) {
    unsigned int u = __float_as_uint(f);
    unsigned int r = (u + 0x7fffu + ((u >> 16) & 1u)) >> 16;
    return (unsigned short)r;
}
__device__ __forceinline__ float bf2f(unsigned short s) {
    return __uint_as_float(((unsigned int)s) << 16);
}
// packed f32x2 -> bf16x2 (v_cvt_pk_bf16_f32 on gfx950 via hip_bf16)
__device__ __forceinline__ unsigned int pk_bf16(float lo, float hi) {
    __hip_bfloat162 h = __float22bfloat162_rn(float2{lo, hi});
    union { __hip_bfloat162 h; unsigned int u; } c;
    c.h = h;
    return c.u;
}

// ---------------------------------------------------------------------------
// prep: convert weights to bf16 chunked layout ws[c][n][kk], n in [0,256),
// kk in [0,32). Coalesced reads (256 threads sweep n for each k-row).
// 60 blocks: ew0(14) ew1(8) ew2(8) W0a(8) W0b(14) uw1(8)
// ---------------------------------------------------------------------------
__global__ __launch_bounds__(256) void prep_weights(
    const float* __restrict__ ew0, const float* __restrict__ ew1,
    const float* __restrict__ ew2, const float* __restrict__ uw0,
    const float* __restrict__ uw1,
    unsigned short* __restrict__ ew0s, unsigned short* __restrict__ ew1s,
    unsigned short* __restrict__ ew2s, unsigned short* __restrict__ w0as,
    unsigned short* __restrict__ w0bs, unsigned short* __restrict__ w1s_)
{
    const int bx = blockIdx.x, t = threadIdx.x;
    const float* srcW; int k0; unsigned short* dst;
    if (bx < 14)      { srcW = ew0; k0 = bx * 32;              dst = ew0s + bx * 8192; }
    else if (bx < 22) { srcW = ew1; k0 = (bx - 14) * 32;       dst = ew1s + (bx - 14) * 8192; }
    else if (bx < 30) { srcW = ew2; k0 = (bx - 22) * 32;       dst = ew2s + (bx - 22) * 8192; }
    else if (bx < 38) { srcW = uw0; k0 = (bx - 30) * 32;       dst = w0as + (bx - 30) * 8192; }
    else if (bx < 52) { srcW = uw0; k0 = 256 + (bx - 38) * 32; dst = w0bs + (bx - 38) * 8192; }
    else              { srcW = uw1; k0 = (bx - 52) * 32;       dst = w1s_ + (bx - 52) * 8192; }
    unsigned short v[32];
    #pragma unroll
    for (int kk = 0; kk < 32; ++kk) v[kk] = f2bf(srcW[(size_t)(k0 + kk) * kC + t]);
    #pragma unroll
    for (int j = 0; j < 4; ++j) *(short8*)(dst + t * 32 + j * 8) = *(short8*)(v + j * 8);
}

// ---------------------------------------------------------------------------
// 16-row-tile GEMM helper for kernelA (1 row-tile x 4 col-tiles per wave).
// ---------------------------------------------------------------------------
__device__ __forceinline__ void gemm_x1_global(
    const unsigned short* __restrict__ x2e, const unsigned short* __restrict__ wsrc,
    int nchunk, int w, int q, int ml, float4v acc[4])
{
    const unsigned short* wp[4];
    #pragma unroll
    for (int ct = 0; ct < 4; ++ct) wp[ct] = wsrc + ((64 * w + 16 * ct + ml) * 32 + q * 8);
    for (int c = 0; c < nchunk; ++c) {
        short8 af = *(const short8*)(x2e + ml * 264 + c * 32 + q * 8);
        short8 bfr[4];
        #pragma unroll
        for (int ct = 0; ct < 4; ++ct) bfr[ct] = *(const short8*)(wp[ct] + c * 8192);
        #pragma unroll
        for (int ct = 0; ct < 4; ++ct)
            acc[ct] = __builtin_amdgcn_mfma_f32_16x16x32_bf16(af, bfr[ct], acc[ct], 0, 0, 0);
    }
}

// ---------------------------------------------------------------------------
// kernelA: 261 blocks.
//   bx 0..3   : hyper chains; bx 4: iou mlp3; bx 5..260: encoder, 16 rows each
//   Z stored PERMUTED: col (64w+16ct+ml) at (64w + 4*ml + ct).
// ---------------------------------------------------------------------------
__global__ __launch_bounds__(256) void kernelA(
    const float* __restrict__ pc, const float* __restrict__ dense,
    const unsigned short* __restrict__ ew0s, const float* __restrict__ eb0,
    const unsigned short* __restrict__ ew1s, const float* __restrict__ eb1,
    const unsigned short* __restrict__ ew2s, const float* __restrict__ eb2,
    const unsigned short* __restrict__ w0as, const float* __restrict__ ub0,
    const float* __restrict__ iou_token, const float* __restrict__ mask_tokens,
    const float* __restrict__ hw0, const float* __restrict__ hb0,
    const float* __restrict__ hw1, const float* __restrict__ hb1,
    const float* __restrict__ hw2, const float* __restrict__ hb2,
    const float* __restrict__ iw0, const float* __restrict__ ib0,
    const float* __restrict__ iw1, const float* __restrict__ ib1,
    const float* __restrict__ iw2, const float* __restrict__ ib2,
    unsigned short* __restrict__ Zbf,      // (B*NC, 256) bf16, PERMUTED cols
    float* __restrict__ hyper_out,         // (3, C)
    float* __restrict__ iou_out)           // (B, 3)
{
    __shared__ unsigned short x2e[16 * 264];   // 8448 B
    __shared__ float va[kC];
    __shared__ float vb[kC];
    const int tid = threadIdx.x, bx = blockIdx.x;

    if (bx >= 5) {
        const int row0 = (bx - 5) * 16;
        const int w = tid >> 6, lane = tid & 63, q = lane >> 4, ml = lane & 15;

        // ---- E0: 448 -> 256, relu ----
        const float* pcr = pc + (size_t)(row0 + ml) * kDIN;
        float4v acc0[4] = {};
        for (int c = 0; c < 14; ++c) {
            float4 f0 = *(const float4*)(pcr + c * 32 + q * 8);
            float4 f1 = *(const float4*)(pcr + c * 32 + q * 8 + 4);
            union { short8 s; unsigned int u[4]; } cv;
            cv.u[0] = pk_bf16(f0.x, f0.y); cv.u[1] = pk_bf16(f0.z, f0.w);
            cv.u[2] = pk_bf16(f1.x, f1.y); cv.u[3] = pk_bf16(f1.z, f1.w);
            short8 af = cv.s;
            #pragma unroll
            for (int ct = 0; ct < 4; ++ct) {
                short8 bfr = *(const short8*)(ew0s + (size_t)c * 8192 + (64 * w + 16 * ct + ml) * 32 + q * 8);
                acc0[ct] = __builtin_amdgcn_mfma_f32_16x16x32_bf16(af, bfr, acc0[ct], 0, 0, 0);
            }
        }
        {
            float bc[4];
            #pragma unroll
            for (int ct = 0; ct < 4; ++ct) bc[ct] = eb0[64 * w + 16 * ct + ml];
            #pragma unroll
            for (int i = 0; i < 4; ++i) {
                int row = 4 * q + i;
                #pragma unroll
                for (int ct = 0; ct < 4; ++ct)
                    x2e[row * 264 + 64 * w + 16 * ct + ml] = f2bf(fmaxf(acc0[ct][i] + bc[ct], 0.0f));
            }
        }
        __syncthreads();

        // ---- E1: 256 -> 256, relu ----
        float4v acc2[4] = {};
        gemm_x1_global(x2e, ew1s, 8, w, q, ml, acc2);
        __syncthreads();
        {
            float bc[4];
            #pragma unroll
            for (int ct = 0; ct < 4; ++ct) bc[ct] = eb1[64 * w + 16 * ct + ml];
            #pragma unroll
            for (int i = 0; i < 4; ++i) {
                int row = 4 * q + i;
                #pragma unroll
                for (int ct = 0; ct < 4; ++ct)
                    x2e[row * 264 + 64 * w + 16 * ct + ml] = f2bf(fmaxf(acc2[ct][i] + bc[ct], 0.0f));
            }
        }
        __syncthreads();

        // ---- E2: 256 -> 256 (linear) + dense_prompt -> src ----
        float4v acc3[4] = {};
        gemm_x1_global(x2e, ew2s, 8, w, q, ml, acc3);
        __syncthreads();
        {
            float bc[4];
            #pragma unroll
            for (int ct = 0; ct < 4; ++ct) bc[ct] = eb2[64 * w + 16 * ct + ml];
            #pragma unroll
            for (int i = 0; i < 4; ++i) {
                int row = 4 * q + i;
                #pragma unroll
                for (int ct = 0; ct < 4; ++ct) {
                    int col = 64 * w + 16 * ct + ml;
                    float v = acc3[ct][i] + bc[ct] + dense[(size_t)(row0 + row) * kC + col];
                    x2e[row * 264 + col] = f2bf(v);
                }
            }
        }
        __syncthreads();

        // ---- EZ: Z = src @ W0a + up_b0 -> bf16 global (permuted cols) ----
        float4v accZ[4] = {};
        gemm_x1_global(x2e, w0as, 8, w, q, ml, accZ);
        {
            float bc[4];
            #pragma unroll
            for (int ct = 0; ct < 4; ++ct) bc[ct] = ub0[64 * w + 16 * ct + ml];
            #pragma unroll
            for (int i = 0; i < 4; ++i) {
                int row = 4 * q + i;
                ushort4v o;
                #pragma unroll
                for (int ct = 0; ct < 4; ++ct) o[ct] = f2bf(accZ[ct][i] + bc[ct]);
                *(ushort4v*)(Zbf + (size_t)(row0 + row) * kC + 64 * w + 4 * ml) = o;
            }
        }
    } else if (bx < 4) {
        const int m = bx;
        va[tid] = mask_tokens[m * kC + tid];
        __syncthreads();
        const float* W = hw0 + (size_t)m * kC * kC;
        float acc = hb0[m * kC + tid];
        for (int d = 0; d < kC; d++) acc = fmaf(va[d], W[d * kC + tid], acc);
        vb[tid] = fmaxf(acc, 0.0f);
        __syncthreads();
        W = hw1 + (size_t)m * kC * kC;
        acc = hb1[m * kC + tid];
        for (int d = 0; d < kC; d++) acc = fmaf(vb[d], W[d * kC + tid], acc);
        va[tid] = fmaxf(acc, 0.0f);
        __syncthreads();
        W = hw2 + (size_t)m * kC * kC;
        acc = hb2[m * kC + tid];
        for (int d = 0; d < kC; d++) acc = fmaf(va[d], W[d * kC + tid], acc);
        if (m >= 1) hyper_out[(m - 1) * kC + tid] = acc;
    } else {
        va[tid] = iou_token[tid];
        __syncthreads();
        float acc = ib0[tid];
        for (int d = 0; d < kC; d++) acc = fmaf(va[d], iw0[d * 256 + tid], acc);
        vb[tid] = fmaxf(acc, 0.0f);
        __syncthreads();
        acc = ib1[tid];
        for (int d = 0; d < 256; d++) acc = fmaf(vb[d], iw1[d * 256 + tid], acc);
        va[tid] = fmaxf(acc, 0.0f);
        __syncthreads();
        if (tid < kM) {
            acc = ib2[tid];
            for (int d = 0; d < 256; d++) acc = fmaf(va[d], iw2[d * kM + tid], acc);
            if (tid >= 1)
                for (int b = 0; b < kB; b++) iou_out[b * 3 + (tid - 1)] = acc;
        }
    }
}

// ---------------------------------------------------------------------------
// main: 32 rows x 256 cols per block (4096 blocks) — smaller acc (2x4 = 32
// AGPR) + launch_bounds(256,4) targets 128-unified-reg boundary -> 4 blocks/CU
// (vs 3), LDS ~21 KB (no longer limiter), finer phase interleave for latency
// hiding. Same math/accumulation order as the 64-row version.
// ---------------------------------------------------------------------------
__global__ __launch_bounds__(256, 4) void main_mfma(
    const unsigned short* __restrict__ Zbf,
    const float* __restrict__ pf,
    const float* __restrict__ iwgt, const int* __restrict__ iidx,
    const unsigned short* __restrict__ w0bs, const unsigned short* __restrict__ w1s_,
    const float* __restrict__ lng, const float* __restrict__ lnb,
    const float* __restrict__ b1v, const float* __restrict__ hyper,
    float* __restrict__ masks)
{
    __shared__ unsigned short buf[32 * 264];    // 16896 B: pf halves (stride 232) then x2 (stride 264)
    __shared__ int   gi[32][3];
    __shared__ float gw[32][3];
    __shared__ float sums[4][32];
    __shared__ float sqs[4][32];
    __shared__ float muA[32];
    __shared__ float rsA[32];
    __shared__ float pd[12][32];

    const int b = blockIdx.y, p0 = blockIdx.x * 32, tid = threadIdx.x;
    const int w = tid >> 6, lane = tid & 63, q = lane >> 4, ml = lane & 15;

    if (tid < 96) {
        int r = tid / 3, k = tid - r * 3;
        int base = (b * kNP + p0 + r) * 3 + k;
        gi[r][k] = iidx[base];
        gw[r][k] = iwgt[base];
    }

    float4v acc[2][4] = {};
    const float* pfb = pf + ((size_t)b * kNP + p0) * kDIN;

    // ---------------- GEMM1: y = pf @ W0b, two K=224 halves via LDS ---------
    #pragma unroll
    for (int h = 0; h < 2; ++h) {
        // stage: 32 rows x 224 cols f32 -> bf16, stride 232 (16B-aligned rows)
        #pragma unroll
        for (int j = 0; j < 4; ++j) {
            int idx = j * 256 + tid;          // 0..895 ; 28 short8 per row-half
            if (idx < 896) {
                int r = idx / 28;
                int co = idx - r * 28;
                const float* g = pfb + (size_t)r * kDIN + h * 224 + co * 8;
                float4 f0 = *(const float4*)g;
                float4 f1 = *(const float4*)(g + 4);
                union { short8 s; unsigned int u[4]; } cv;
                cv.u[0] = pk_bf16(f0.x, f0.y); cv.u[1] = pk_bf16(f0.z, f0.w);
                cv.u[2] = pk_bf16(f1.x, f1.y); cv.u[3] = pk_bf16(f1.z, f1.w);
                *(short8*)&buf[r * 232 + co * 8] = cv.s;
            }
        }
        __syncthreads();
        // fragment base: (64*w + 16*ct + ml)*32 + q*8 = 2048w + 512ct + 32ml + 8q
        const unsigned short* wh = w0bs + (size_t)h * 7 * 8192 + ((64 * w + ml) * 32 + q * 8);
        for (int c = 0; c < 7; ++c) {
            short8 af[2], bfr[4];
            #pragma unroll
            for (int rt = 0; rt < 2; ++rt)
                af[rt] = *(const short8*)&buf[(16 * rt + ml) * 232 + c * 32 + q * 8];
            #pragma unroll
            for (int ct = 0; ct < 4; ++ct)
                bfr[ct] = *(const short8*)(wh + (size_t)c * 8192 + 512 * ct);
            #pragma unroll
            for (int rt = 0; rt < 2; ++rt)
                #pragma unroll
                for (int ct = 0; ct < 4; ++ct)
                    acc[rt][ct] = __builtin_amdgcn_mfma_f32_16x16x32_bf16(af[rt], bfr[ct], acc[rt][ct], 0, 0, 0);
        }
        __syncthreads();   // pf half consumed before restage/overwrite
    }

    // ------- interp add via permuted-Z gather (one ushort4 per row,k) -------
    {
        const unsigned short* zb = Zbf + (size_t)b * kNC * kC + 64 * w + 4 * ml;
        #pragma unroll
        for (int rt = 0; rt < 2; ++rt)
            #pragma unroll
            for (int i = 0; i < 4; ++i) {
                int row = 16 * rt + 4 * q + i;
                #pragma unroll
                for (int k = 0; k < 3; ++k) {
                    float wk = gw[row][k];
                    ushort4v z = *(const ushort4v*)(zb + (size_t)gi[row][k] * kC);
                    #pragma unroll
                    for (int ct = 0; ct < 4; ++ct)
                        acc[rt][ct][i] = fmaf(wk, bf2f(z[ct]), acc[rt][ct][i]);
                }
            }
    }

    // ---------------- LayerNorm stats ----------------
    {
        float s[2][4], s2[2][4];
        #pragma unroll
        for (int rt = 0; rt < 2; ++rt)
            #pragma unroll
            for (int i = 0; i < 4; ++i) {
                float a = 0.f, b2 = 0.f;
                #pragma unroll
                for (int ct = 0; ct < 4; ++ct) {
                    float v = acc[rt][ct][i];
                    a += v; b2 = fmaf(v, v, b2);
                }
                s[rt][i] = a; s2[rt][i] = b2;
            }
        #pragma unroll
        for (int o = 1; o < 16; o <<= 1) {
            #pragma unroll
            for (int rt = 0; rt < 2; ++rt)
                #pragma unroll
                for (int i = 0; i < 4; ++i) {
                    s[rt][i]  += __shfl_xor(s[rt][i], o);
                    s2[rt][i] += __shfl_xor(s2[rt][i], o);
                }
        }
        if (ml == 0) {
            #pragma unroll
            for (int rt = 0; rt < 2; ++rt)
                #pragma unroll
                for (int i = 0; i < 4; ++i) {
                    int row = 16 * rt + 4 * q + i;
                    sums[w][row] = s[rt][i];
                    sqs[w][row]  = s2[rt][i];
                }
        }
    }
    __syncthreads();
    if (tid < 32) {
        float ts = sums[0][tid] + sums[1][tid] + sums[2][tid] + sums[3][tid];
        float tq = sqs[0][tid] + sqs[1][tid] + sqs[2][tid] + sqs[3][tid];
        float mu = ts * (1.0f / 256.0f);
        float var = tq * (1.0f / 256.0f) - mu * mu;
        muA[tid] = mu;
        rsA[tid] = rsqrtf(var + 1e-5f);
    }
    __syncthreads();

    // ---------------- normalize + GELU -> x2 (bf16, LDS stride 264) --------
    {
        float gc[4], oc[4];
        #pragma unroll
        for (int ct = 0; ct < 4; ++ct) {
            gc[ct] = lng[64 * w + 16 * ct + ml];
            oc[ct] = lnb[64 * w + 16 * ct + ml];
        }
        #pragma unroll
        for (int rt = 0; rt < 2; ++rt)
            #pragma unroll
            for (int i = 0; i < 4; ++i) {
                int row = 16 * rt + 4 * q + i;
                float mu = muA[row], rs = rsA[row];
                #pragma unroll
                for (int ct = 0; ct < 4; ++ct) {
                    float v = (acc[rt][ct][i] - mu) * rs * gc[ct] + oc[ct];
                    buf[row * 264 + 64 * w + 16 * ct + ml] = f2bf(gelu_exact(v));
                }
            }
    }
    __syncthreads();

    // ---------------- GEMM2: K=256, 8 chunks, NO barriers ----------------
    float4v acc2[2][4] = {};
    {
        const unsigned short* wp[4];
        #pragma unroll
        for (int ct = 0; ct < 4; ++ct) wp[ct] = w1s_ + ((64 * w + 16 * ct + ml) * 32 + q * 8);
        for (int c = 0; c < 8; ++c) {
            short8 af[2], bfr[4];
            #pragma unroll
            for (int rt = 0; rt < 2; ++rt)
                af[rt] = *(const short8*)&buf[(16 * rt + ml) * 264 + c * 32 + q * 8];
            #pragma unroll
            for (int ct = 0; ct < 4; ++ct) bfr[ct] = *(const short8*)(wp[ct] + c * 8192);
            #pragma unroll
            for (int rt = 0; rt < 2; ++rt)
                #pragma unroll
                for (int ct = 0; ct < 4; ++ct)
                    acc2[rt][ct] = __builtin_amdgcn_mfma_f32_16x16x32_bf16(af[rt], bfr[ct], acc2[rt][ct], 0, 0, 0);
        }
    }

    // ---------------- GELU + hyper partial dots ----------------
    {
        float bc1[4], hy[3][4];
        #pragma unroll
        for (int ct = 0; ct < 4; ++ct) bc1[ct] = b1v[64 * w + 16 * ct + ml];
        #pragma unroll
        for (int m = 0; m < 3; ++m)
            #pragma unroll
            for (int ct = 0; ct < 4; ++ct) hy[m][ct] = hyper[m * kC + 64 * w + 16 * ct + ml];
        float pdl[3][2][4] = {};
        #pragma unroll
        for (int rt = 0; rt < 2; ++rt)
            #pragma unroll
            for (int ct = 0; ct < 4; ++ct)
                #pragma unroll
                for (int i = 0; i < 4; ++i) {
                    float u = gelu_exact(acc2[rt][ct][i] + bc1[ct]);
                    #pragma unroll
                    for (int m = 0; m < 3; ++m) pdl[m][rt][i] = fmaf(u, hy[m][ct], pdl[m][rt][i]);
                }
        #pragma unroll
        for (int o = 1; o < 16; o <<= 1) {
            #pragma unroll
            for (int m = 0; m < 3; ++m)
                #pragma unroll
                for (int rt = 0; rt < 2; ++rt)
                    #pragma unroll
                    for (int i = 0; i < 4; ++i)
                        pdl[m][rt][i] += __shfl_xor(pdl[m][rt][i], o);
        }
        if (ml < 3) {
            const int m = ml;
            #pragma unroll
            for (int rt = 0; rt < 2; ++rt)
                #pragma unroll
                for (int i = 0; i < 4; ++i)
                    pd[w * 3 + m][16 * rt + 4 * q + i] = pdl[m][rt][i];
        }
    }
    __syncthreads();
    if (tid < 96) {
        int m = tid >> 5, r = tid & 31;
        float v = pd[0 + m][r] + pd[3 + m][r] + pd[6 + m][r] + pd[9 + m][r];
        masks[((size_t)b * 3 + m) * kNP + p0 + r] = v;
    }
}

// ---------------------------------------------------------------------------
extern "C" void kernel_launch(void* const* d_in, const int* in_sizes, int n_in,
                              void* d_out, int out_size, void* d_ws, size_t ws_size,
                              hipStream_t stream) {
    const float* pc_emb  = (const float*)d_in[0];
    const float* dense   = (const float*)d_in[3];
    const float* pf      = (const float*)d_in[4];
    const float* iwgt    = (const float*)d_in[5];
    const int*   iidx    = (const int*)d_in[6];
    const float* iou_tok = (const float*)d_in[7];
    const float* mtok    = (const float*)d_in[8];
    const float* ew0 = (const float*)d_in[9];
    const float* eb0 = (const float*)d_in[10];
    const float* ew1 = (const float*)d_in[11];
    const float* eb1 = (const float*)d_in[12];
    const float* ew2 = (const float*)d_in[13];
    const float* eb2 = (const float*)d_in[14];
    const float* uw0 = (const float*)d_in[15];
    const float* ub0 = (const float*)d_in[16];
    const float* lng = (const float*)d_in[17];
    const float* lnb = (const float*)d_in[18];
    const float* uw1 = (const float*)d_in[19];
    const float* ub1 = (const float*)d_in[20];
    const float* hw0 = (const float*)d_in[21];
    const float* hb0 = (const float*)d_in[22];
    const float* hw1 = (const float*)d_in[23];
    const float* hb1 = (const float*)d_in[24];
    const float* hw2 = (const float*)d_in[25];
    const float* hb2 = (const float*)d_in[26];
    const float* iw0 = (const float*)d_in[27];
    const float* ib0 = (const float*)d_in[28];
    const float* iw1 = (const float*)d_in[29];
    const float* ib1 = (const float*)d_in[30];
    const float* iw2 = (const float*)d_in[31];
    const float* ib2 = (const float*)d_in[32];

    float* out = (float*)d_out;   // masks (4,3,32768) then iou (4,3)

    // workspace layout (bytes)
    char* ws = (char*)d_ws;
    unsigned short* Zbf  = (unsigned short*)(ws + 0);        // 2,097,152
    float* ws_hyper      = (float*)(ws + 2097152);           // 3,072
    unsigned short* ew0s = (unsigned short*)(ws + 2100224);  // 229,376
    unsigned short* ew1s = (unsigned short*)(ws + 2329600);  // 131,072
    unsigned short* ew2s = (unsigned short*)(ws + 2460672);  // 131,072
    unsigned short* w0as = (unsigned short*)(ws + 2591744);  // 131,072
    unsigned short* w0bs = (unsigned short*)(ws + 2722816);  // 229,376
    unsigned short* w1s_ = (unsigned short*)(ws + 2952192);  // 131,072

    prep_weights<<<60, 256, 0, stream>>>(ew0, ew1, ew2, uw0, uw1,
                                         ew0s, ew1s, ew2s, w0as, w0bs, w1s_);

    kernelA<<<261, 256, 0, stream>>>(
        pc_emb, dense, ew0s, eb0, ew1s, eb1, ew2s, eb2, w0as, ub0,
        iou_tok, mtok, hw0, hb0, hw1, hb1, hw2, hb2,
        iw0, ib0, iw1, ib1, iw2, ib2,
        Zbf, ws_hyper, out + (size_t)kB * 3 * kNP);

    main_mfma<<<dim3(kNP / 32, kB), 256, 0, stream>>>(
        Zbf, pf, iwgt, iidx, w0bs, w1s_,
        lng, lnb, ub1, ws_hyper, out);
}